// Round 4
// baseline (2257.597 us; speedup 1.0000x reference)
//
#include <hip/hip_runtime.h>

// GRU: B=256, T=2048, I=2, H=128. One workgroup (512 thr = 8 waves) per batch.
// Thread owns 6 rows x 16-col slice of W_hh (24 float4 in VGPRs).
// Lane mapping within a 16-lane DPP row: q = (r&3)|((r>>1)&4) (slice 0..7),
// jbit = (r>>2)&1; the 8-lane reduce group = quads {Qk, Qk+2}, so reduction is
// quad_perm xor1, xor2, then row_ror:8 (direction-unambiguous) — all VALU DPP,
// no ds_swizzle (R3's __shfl_xor went through the LDS pipe and dominated).
// h double-buffered in LDS, 20-word slice stride (conflict-free, 16B aligned).
// One __syncthreads per step.

#define BB 256
#define TT 2048
#define HH 128
#define NT 512
#define SLW 20              // words per 16-float h slice (+4 pad)
#define HWORDS (8 * SLW)    // 160

#define PIN(v) asm volatile("" : "+v"(v))
#define PIN4(f) do { PIN((f).x); PIN((f).y); PIN((f).z); PIN((f).w); } while (0)

// p += DPP-moved(p); CTRL must be a constant expression
#define DPP_ADD(p, CTRL) do { \
    int _m = __builtin_amdgcn_update_dpp(0, __float_as_int(p), (CTRL), 0xF, 0xF, true); \
    (p) += __int_as_float(_m); } while (0)

#define QP_XOR1 0xB1   // quad_perm [1,0,3,2]
#define QP_XOR2 0x4E   // quad_perm [2,3,0,1]
#define ROW_ROR8 0x128 // rotate 16-lane row by 8 (self-inverse)

__device__ __forceinline__ float fast_sigmoid(float v) {
    return 1.0f / (1.0f + __expf(-v));
}
__device__ __forceinline__ float fast_tanh(float v) {
    v = fminf(fmaxf(v, -30.0f), 30.0f);
    float e = __expf(2.0f * v);
    return (e - 1.0f) / (e + 1.0f);
}

__global__ __launch_bounds__(NT)
__attribute__((amdgpu_waves_per_eu(2, 2)))
void gru_seq_kernel(
    const float* __restrict__ x,        // [B, T, 2]
    const int*   __restrict__ lengths,  // [B]
    const float* __restrict__ W_ih,     // [384, 2]
    const float* __restrict__ W_hh,     // [384, 128]
    const float* __restrict__ b_ih,     // [384]
    const float* __restrict__ b_hh,     // [384]
    const float* __restrict__ head_w,   // [128]
    const float* __restrict__ head_b,   // [1]
    float* __restrict__ out)            // [B]
{
    __shared__ __align__(16) float x_lds[TT * 2];       // 16 KB
    __shared__ __align__(16) float h_lds[2][HWORDS];    // 1.25 KB
    __shared__ float red[64];

    const int tid = threadIdx.x;
    const int r16 = tid & 15;
    const int q   = (r16 & 3) | ((r16 >> 1) & 4);            // h slice 0..7
    const int j   = ((tid >> 4) << 1) | ((r16 >> 2) & 1);    // hidden pair 0..63
    const int b   = blockIdx.x;
    const int len = lengths[b];

    // --- weights: 6 rows (gates r,z,n x pair p) x 16-col slice ---
    float4 wv[24];
    #pragma unroll
    for (int rr = 0; rr < 6; ++rr) {
        const int gate = rr >> 1, p = rr & 1;
        const float4* Wp = (const float4*)(W_hh + (size_t)(gate * HH + 2 * j + p) * HH + 16 * q);
        #pragma unroll
        for (int c = 0; c < 4; ++c) wv[rr * 4 + c] = Wp[c];
    }
    #pragma unroll
    for (int i = 0; i < 24; ++i) PIN4(wv[i]);

    // --- consumer (q==0) constants for hidden indices 2j, 2j+1 ---
    float2 wi_r[2] = {{0,0},{0,0}}, wi_z[2] = {{0,0},{0,0}}, wi_n[2] = {{0,0},{0,0}};
    float br[2] = {0,0}, bz[2] = {0,0}, bnn[2] = {0,0}, bhn[2] = {0,0}, hwv[2] = {0,0};
    if (q == 0) {
        #pragma unroll
        for (int p = 0; p < 2; ++p) {
            const int hj = 2 * j + p;
            wi_r[p] = ((const float2*)W_ih)[hj];
            wi_z[p] = ((const float2*)W_ih)[HH + hj];
            wi_n[p] = ((const float2*)W_ih)[2 * HH + hj];
            br[p]  = b_ih[hj] + b_hh[hj];
            bz[p]  = b_ih[HH + hj] + b_hh[HH + hj];
            bnn[p] = b_ih[2 * HH + hj];
            bhn[p] = b_hh[2 * HH + hj];
            hwv[p] = head_w[hj];
        }
    }

    // --- stage x[b] into LDS; zero both h buffers ---
    {
        const float4* xb4 = (const float4*)(x + (size_t)b * TT * 2);
        float4* xl4 = (float4*)x_lds;
        #pragma unroll
        for (int i = tid; i < TT * 2 / 4; i += NT) xl4[i] = xb4[i];
    }
    for (int i = tid; i < 2 * HWORDS; i += NT) ((float*)h_lds)[i] = 0.f;

    __syncthreads();

    float hreg0 = 0.f, hreg1 = 0.f;
    int buf = 0;
    const float2* x2 = (const float2*)x_lds;

    for (int t = 0; t < len; ++t) {
        const float2 xt = x2[t];

        const float4* hb = (const float4*)&h_lds[buf][SLW * q];
        const float4 hv0 = hb[0], hv1 = hb[1], hv2 = hb[2], hv3 = hb[3];

        float acc[6];
        #pragma unroll
        for (int rr = 0; rr < 6; ++rr) {
            const float4 w0 = wv[rr * 4], w1 = wv[rr * 4 + 1];
            const float4 w2 = wv[rr * 4 + 2], w3 = wv[rr * 4 + 3];
            float a = 0.f;
            a = fmaf(w0.x, hv0.x, fmaf(w0.y, hv0.y, fmaf(w0.z, hv0.z, fmaf(w0.w, hv0.w, a))));
            a = fmaf(w1.x, hv1.x, fmaf(w1.y, hv1.y, fmaf(w1.z, hv1.z, fmaf(w1.w, hv1.w, a))));
            a = fmaf(w2.x, hv2.x, fmaf(w2.y, hv2.y, fmaf(w2.z, hv2.z, fmaf(w2.w, hv2.w, a))));
            a = fmaf(w3.x, hv3.x, fmaf(w3.y, hv3.y, fmaf(w3.z, hv3.z, fmaf(w3.w, hv3.w, a))));
            acc[rr] = a;
        }

        // 8-lane reduce (quads Qk & Qk+2): pure-VALU DPP
        #pragma unroll
        for (int rr = 0; rr < 6; ++rr) {
            DPP_ADD(acc[rr], QP_XOR1);
            DPP_ADD(acc[rr], QP_XOR2);
            DPP_ADD(acc[rr], ROW_ROR8);
        }

        if (q == 0) {
            // p = 0
            {
                const float rg = fast_sigmoid(fmaf(wi_r[0].x, xt.x, fmaf(wi_r[0].y, xt.y, br[0])) + acc[0]);
                const float zg = fast_sigmoid(fmaf(wi_z[0].x, xt.x, fmaf(wi_z[0].y, xt.y, bz[0])) + acc[2]);
                const float xn = fmaf(wi_n[0].x, xt.x, fmaf(wi_n[0].y, xt.y, bnn[0]));
                const float ng = fast_tanh(fmaf(rg, acc[4] + bhn[0], xn));
                hreg0 = ng + zg * (hreg0 - ng);
            }
            // p = 1
            {
                const float rg = fast_sigmoid(fmaf(wi_r[1].x, xt.x, fmaf(wi_r[1].y, xt.y, br[1])) + acc[1]);
                const float zg = fast_sigmoid(fmaf(wi_z[1].x, xt.x, fmaf(wi_z[1].y, xt.y, bz[1])) + acc[3]);
                const float xn = fmaf(wi_n[1].x, xt.x, fmaf(wi_n[1].y, xt.y, bnn[1]));
                const float ng = fast_tanh(fmaf(rg, acc[5] + bhn[1], xn));
                hreg1 = ng + zg * (hreg1 - ng);
            }
            const int hi = 2 * j;    // even; hi and hi+1 share a slice
            float* dst = &h_lds[buf ^ 1][SLW * (hi >> 4) + (hi & 15)];
            *(float2*)dst = make_float2(hreg0, hreg1);
        }
        __syncthreads();
        buf ^= 1;
    }

    // --- head: out[b] = dot(h, head_w) + head_b ---
    if (q == 0) red[j] = fmaf(hreg0, hwv[0], hreg1 * hwv[1]);
    __syncthreads();
    if (tid < 64) {
        float v = red[tid];
        #pragma unroll
        for (int off = 32; off > 0; off >>= 1) v += __shfl_xor(v, off, 64);
        if (tid == 0) out[b] = v + head_b[0];
    }
}

extern "C" void kernel_launch(void* const* d_in, const int* in_sizes, int n_in,
                              void* d_out, int out_size, void* d_ws, size_t ws_size,
                              hipStream_t stream) {
    const float* x      = (const float*)d_in[0];
    const int*   len    = (const int*)  d_in[1];
    const float* W_ih   = (const float*)d_in[2];
    const float* W_hh   = (const float*)d_in[3];
    const float* b_ih   = (const float*)d_in[4];
    const float* b_hh   = (const float*)d_in[5];
    const float* head_w = (const float*)d_in[6];
    const float* head_b = (const float*)d_in[7];
    float* out = (float*)d_out;

    gru_seq_kernel<<<BB, NT, 0, stream>>>(x, len, W_ih, W_hh, b_ih, b_hh,
                                          head_w, head_b, out);
}

// Round 5
// 1305.696 us; speedup vs baseline: 1.7290x; 1.7290x over previous
//
#include <hip/hip_runtime.h>

// GRU: B=256, T=2048, I=2, H=128. One workgroup (512 thr = 8 waves) per batch.
// R2 structure (best measured: 1409 us): thread (q=tid&3, j=tid>>2) owns the
// q-th 32-col slice of gate rows {j, 128+j, 256+j}; h double-buffered in LDS
// (40-word slice stride, conflict-free broadcast reads); one barrier/step.
// R5 deltas vs R2:
//  (1) cross-lane reduce = 2x v_add_f32_dpp (quad_perm xor1/xor2) inline asm
//      with embedded s_nop 1 for the VALU->DPP hazard — removes the 6
//      __shfl_xor ds_swizzles from the LDS pipe (R2 was LDS-pipe-bound).
//  (2) packed fp32 FMA (v_pk_fma_f32) via __builtin_elementwise_fma on
//      float2 vectors — halves FMA issue; falls back to scalar if unselected.

#define BB 256
#define TT 2048
#define HH 128
#define NT 512
#define HWORDS 160   // 4 slices x 40 words (32 data + 8 pad)

typedef float v4f __attribute__((ext_vector_type(4)));
typedef float v2f __attribute__((ext_vector_type(2)));

#define LO2(v) __builtin_shufflevector((v), (v), 0, 1)
#define HI2(v) __builtin_shufflevector((v), (v), 2, 3)

// x += quad_perm(x); s_nop 1 covers the 2-wait-state VALU->DPP hazard
// (hazard recognizer cannot see inside inline asm).
#define DPP_ADD_Q(x, QPSTR) do { float _d;                                   \
    asm volatile("s_nop 1\n\t"                                               \
                 "v_add_f32_dpp %0, %1, %1 " QPSTR                           \
                 " row_mask:0xf bank_mask:0xf"                               \
                 : "=v"(_d) : "v"(x));                                       \
    (x) = _d; } while (0)

__device__ __forceinline__ float fast_sigmoid(float v) {
    return 1.0f / (1.0f + __expf(-v));
}
__device__ __forceinline__ float fast_tanh(float v) {
    v = fminf(fmaxf(v, -30.0f), 30.0f);
    float e = __expf(2.0f * v);
    return (e - 1.0f) / (e + 1.0f);
}

__global__ __launch_bounds__(NT, 2) void gru_seq_kernel(
    const float* __restrict__ x,        // [B, T, 2]
    const int*   __restrict__ lengths,  // [B]
    const float* __restrict__ W_ih,     // [384, 2]
    const float* __restrict__ W_hh,     // [384, 128]
    const float* __restrict__ b_ih,     // [384]
    const float* __restrict__ b_hh,     // [384]
    const float* __restrict__ head_w,   // [128]
    const float* __restrict__ head_b,   // [1]
    float* __restrict__ out)            // [B]
{
    __shared__ __align__(16) float x_lds[TT * 2];        // 16 KB
    __shared__ __align__(16) float h_lds[2][HWORDS];     // 1.25 KB
    __shared__ float red[8];

    const int tid = threadIdx.x;
    const int q = tid & 3;          // 32-col slice
    const int j = tid >> 2;         // hidden index 0..127
    const int b = blockIdx.x;
    const int len = lengths[b];

    // --- weights for this thread's 3 row-slices ---
    v4f wr[8], wz[8], wn[8];
    {
        const v4f* Wr = (const v4f*)(W_hh + (size_t)j * HH + q * 32);
        const v4f* Wz = (const v4f*)(W_hh + (size_t)(HH + j) * HH + q * 32);
        const v4f* Wn = (const v4f*)(W_hh + (size_t)(2 * HH + j) * HH + q * 32);
        #pragma unroll
        for (int i = 0; i < 8; ++i) { wr[i] = Wr[i]; wz[i] = Wz[i]; wn[i] = Wn[i]; }
    }

    // per-j scalar params (only q==0 lane uses them)
    float wir0 = 0.f, wir1 = 0.f, bir = 0.f;
    float wiz0 = 0.f, wiz1 = 0.f, biz = 0.f;
    float win0 = 0.f, win1 = 0.f, bin = 0.f;
    float bhr = 0.f, bhz = 0.f, bhn = 0.f, hw = 0.f;
    if (q == 0) {
        wir0 = W_ih[j * 2];            wir1 = W_ih[j * 2 + 1];            bir = b_ih[j];
        wiz0 = W_ih[(HH + j) * 2];     wiz1 = W_ih[(HH + j) * 2 + 1];     biz = b_ih[HH + j];
        win0 = W_ih[(2 * HH + j) * 2]; win1 = W_ih[(2 * HH + j) * 2 + 1]; bin = b_ih[2 * HH + j];
        bhr = b_hh[j]; bhz = b_hh[HH + j]; bhn = b_hh[2 * HH + j];
        hw = head_w[j];
    }

    // --- stage x[b] into LDS (float4, coalesced) ---
    {
        const float4* xb4 = (const float4*)(x + (size_t)b * TT * 2);
        float4* xl4 = (float4*)x_lds;
        #pragma unroll
        for (int i = tid; i < TT * 2 / 4; i += NT) xl4[i] = xb4[i];
    }
    // zero both h buffers
    for (int i = tid; i < 2 * HWORDS; i += NT) ((float*)h_lds)[i] = 0.f;

    __syncthreads();

    float h_reg = 0.0f;   // h[j] held by q==0 lanes
    int buf = 0;
    const float2* x2 = (const float2*)x_lds;

    for (int t = 0; t < len; ++t) {
        const float2 xt = x2[t];
        const float x0 = xt.x, x1 = xt.y;

        // read this thread's h slice (broadcast within quad, banks disjoint across q)
        const v4f* hb = (const v4f*)&h_lds[buf][40 * q];
        v4f hv[8];
        #pragma unroll
        for (int i = 0; i < 8; ++i) hv[i] = hb[i];

        // packed-fp32 dot products: 2 v2f accumulators per gate
        v2f arA = {0.f, 0.f}, arB = {0.f, 0.f};
        v2f azA = {0.f, 0.f}, azB = {0.f, 0.f};
        v2f anA = {0.f, 0.f}, anB = {0.f, 0.f};
        #pragma unroll
        for (int i = 0; i < 8; ++i) {
            const v2f hl = LO2(hv[i]), hh = HI2(hv[i]);
            arA = __builtin_elementwise_fma(LO2(wr[i]), hl, arA);
            arB = __builtin_elementwise_fma(HI2(wr[i]), hh, arB);
            azA = __builtin_elementwise_fma(LO2(wz[i]), hl, azA);
            azB = __builtin_elementwise_fma(HI2(wz[i]), hh, azB);
            anA = __builtin_elementwise_fma(LO2(wn[i]), hl, anA);
            anB = __builtin_elementwise_fma(HI2(wn[i]), hh, anB);
        }
        float ar = (arA.x + arA.y) + (arB.x + arB.y);
        float az = (azA.x + azA.y) + (azB.x + azB.y);
        float an = (anA.x + anA.y) + (anB.x + anB.y);

        // combine q-slices: intra-quad DPP adds (pure VALU, no LDS pipe)
        DPP_ADD_Q(ar, "quad_perm:[1,0,3,2]");
        DPP_ADD_Q(ar, "quad_perm:[2,3,0,1]");
        DPP_ADD_Q(az, "quad_perm:[1,0,3,2]");
        DPP_ADD_Q(az, "quad_perm:[2,3,0,1]");
        DPP_ADD_Q(an, "quad_perm:[1,0,3,2]");
        DPP_ADD_Q(an, "quad_perm:[2,3,0,1]");

        if (q == 0) {
            const float r  = fast_sigmoid(fmaf(wir0, x0, fmaf(wir1, x1, bir)) + ar + bhr);
            const float z  = fast_sigmoid(fmaf(wiz0, x0, fmaf(wiz1, x1, biz)) + az + bhz);
            const float hn = an + bhn;
            const float xn = fmaf(win0, x0, fmaf(win1, x1, bin));
            const float n  = fast_tanh(fmaf(r, hn, xn));
            h_reg = n + z * (h_reg - n);
            h_lds[buf ^ 1][40 * (j >> 5) + (j & 31)] = h_reg;
        }
        __syncthreads();
        buf ^= 1;
    }

    // --- head: out[b] = dot(h, head_w) + head_b ---
    float p = (q == 0) ? h_reg * hw : 0.0f;
    #pragma unroll
    for (int off = 32; off > 0; off >>= 1) p += __shfl_xor(p, off);
    const int wid = tid >> 6;
    if ((tid & 63) == 0) red[wid] = p;
    __syncthreads();
    if (tid == 0) {
        float s = red[0];
        #pragma unroll
        for (int i = 1; i < 8; ++i) s += red[i];
        out[b] = s + head_b[0];
    }
}

extern "C" void kernel_launch(void* const* d_in, const int* in_sizes, int n_in,
                              void* d_out, int out_size, void* d_ws, size_t ws_size,
                              hipStream_t stream) {
    const float* x      = (const float*)d_in[0];
    const int*   len    = (const int*)  d_in[1];
    const float* W_ih   = (const float*)d_in[2];
    const float* W_hh   = (const float*)d_in[3];
    const float* b_ih   = (const float*)d_in[4];
    const float* b_hh   = (const float*)d_in[5];
    const float* head_w = (const float*)d_in[6];
    const float* head_b = (const float*)d_in[7];
    float* out = (float*)d_out;

    gru_seq_kernel<<<BB, NT, 0, stream>>>(x, len, W_ih, W_hh, b_ih, b_hh,
                                          head_w, head_b, out);
}